// Round 21
// baseline (2207.415 us; speedup 1.0000x reference)
//
#include <hip/hip_runtime.h>
#include <hip/hip_bf16.h>
#include <math.h>

#define Bd 128
#define Sd 256
#define Ad 8
#define Ed 300
#define Hd 300
#define EP 320
#define Pd 3
#define UC 5      // unit chunks (64 units each)
#define BG 8      // batch groups (16 rows each)

typedef __attribute__((ext_vector_type(8))) short bfrag;   // 8 bf16 (4 VGPRs)
typedef __attribute__((ext_vector_type(4))) float f32x4;   // MFMA acc / 16B float chunk
typedef __attribute__((ext_vector_type(4))) int i32x4;     // 16B chunk

// ---- workspace layout (bytes) ----
#define OFF_LENS   0u           // int[128*4]
#define OFF_FLAGS  4096u        // int[1024]: L2 flags [(side*8+bg)*16 + uc*2+w]; IC at +512 ints
#define OFF_VA     8192u        // float[128*320]
#define OFF_VS     172032u      // float[128*320]
#define OFF_U      335872u      // float[128*320]
#define OFF_C      892928u      // float[128*256]
#define OFF_HF     1024000u     // ushort[2 side][8 bg][2 parity][10 kt][64 lane][8]
#define OFF_PART   1351680u     // float[2*8*5*4][16][256] = 10.49MB
#define OFF_WF     11837440u    // ushort[2 side][2 mat][3 g][20 ut][10 kt][64][8]
#define OFF_W1B    14295040u    // ushort[320*320]
#define OFF_XF     14499840u    // ushort[2 side][256 t][8 bg][10 kt][64][8] = 41.94MB
#define OFF_MEMW   14499840u    // overlays XF (XF dead after k_gru)
#define WS_NEEDED  56442880u

__device__ __forceinline__ unsigned short f2bf(float f) {
    __hip_bfloat16 h = __float2bfloat16(f);
    return *reinterpret_cast<unsigned short*>(&h);
}
__device__ __forceinline__ float bf2f(unsigned short u) {
    __hip_bfloat16 h = *reinterpret_cast<__hip_bfloat16*>(&u);
    return __bfloat162float(h);
}
__device__ __forceinline__ float sigm(float x) {
    return __builtin_amdgcn_rcpf(1.f + __expf(-x));
}
__device__ __forceinline__ float fast_tanh(float x) {
    x = fminf(fmaxf(x, -15.f), 15.f);
    float e = __expf(2.f * x);
    return (e - 1.f) * __builtin_amdgcn_rcpf(e + 1.f);
}

// XCD-L2-coherent DATA ops (sc0 store->shared-L2, proven R9/R13).
// R11 lesson: flags must NEVER be polled with plain loads -> atomic RMW only
// (atomics execute at the L2 coherence point, L1 cannot serve them).
__device__ __forceinline__ bfrag l2_load16b(const void* p) {
    bfrag v;
    asm volatile("global_load_dwordx4 %0, %1, off sc0"
                 : "=v"(v) : "v"(p) : "memory");
    return v;  // NOT ready until s_waitcnt vmcnt
}
__device__ __forceinline__ void l2_store16(void* p, i32x4 v) {
    asm volatile("global_store_dwordx4 %0, %1, off sc0"
                 :: "v"(p), "v"(v) : "memory");
}

// ---------------- prep: x embeddings + GRU weights (fused producers) --------
__global__ void k_prep(const float* __restrict__ embed, const int* __restrict__ xl,
                       const int* __restrict__ xr, unsigned short* __restrict__ XF,
                       const float* __restrict__ wih_l, const float* __restrict__ whh_l,
                       const float* __restrict__ wih_r, const float* __restrict__ whh_r,
                       unsigned short* __restrict__ WF) {
    if (blockIdx.x < 512) {
        // ---- x embeddings, fragment-major (vectorized stores) ----
        int side = blockIdx.x >> 8;
        int t = blockIdx.x & 255;
        const int* xs = side ? xr : xl;
        __shared__ int rows_s[Bd];
        if (threadIdx.x < Bd) rows_s[threadIdx.x] = xs[threadIdx.x*Sd + t];
        __syncthreads();
        unsigned short* dst = XF + ((size_t)(side*Sd + t))*40960;
        for (int v8 = threadIdx.x; v8 < 5120; v8 += 256) {
            int idx = v8 << 3;
            int bt = idx / 5120;
            int r1 = idx - bt*5120;
            int kt = r1 >> 9;
            int r2 = r1 & 511;
            int lane = r2 >> 3;
            int b = bt*16 + (lane & 15);
            int kk = kt*32 + (lane >> 4)*8;
            const float* src = embed + (size_t)rows_s[b]*Ed + kk;
            unsigned short tmp[8];
            if (kk + 8 <= Ed) {
                f32x4 f0 = *(const f32x4*)(src);
                f32x4 f1 = *(const f32x4*)(src + 4);
                #pragma unroll
                for (int j = 0; j < 4; ++j) { tmp[j] = f2bf(f0[j]); tmp[4+j] = f2bf(f1[j]); }
            } else {
                #pragma unroll
                for (int j = 0; j < 8; ++j)
                    tmp[j] = (kk + j < Ed) ? f2bf(src[j]) : (unsigned short)0;
            }
            *(bfrag*)(dst + idx) = *(const bfrag*)tmp;
        }
    } else {
        // ---- GRU weights, fragment-major (vectorized stores) ----
        int bid = blockIdx.x - 512;        // ((side*2+mat)*3+g)*20+ut
        int side = bid / 120;
        int r = bid - side*120;
        int mat = r / 60; r -= mat*60;
        int g = r / 20;
        int ut = r - g*20;
        const float* W = mat ? (side ? whh_r : whh_l) : (side ? wih_r : wih_l);
        unsigned short* dst = WF + (size_t)bid*5120;
        for (int v8 = threadIdx.x; v8 < 640; v8 += 256) {
            int idx = v8 << 3;
            int kt = idx >> 9;
            int r2 = idx & 511;
            int lane = r2 >> 3;
            int unit = ut*16 + (lane & 15);
            int kk = kt*32 + (lane >> 4)*8;
            unsigned short tmp[8];
            if (unit < Hd && kk + 8 <= Ed) {
                const float* src = W + (size_t)(g*Hd + unit)*Ed + kk;
                f32x4 f0 = *(const f32x4*)(src);
                f32x4 f1 = *(const f32x4*)(src + 4);
                #pragma unroll
                for (int j = 0; j < 4; ++j) { tmp[j] = f2bf(f0[j]); tmp[4+j] = f2bf(f1[j]); }
            } else {
                #pragma unroll
                for (int j = 0; j < 8; ++j) {
                    float v = (unit < Hd && kk + j < Ed) ? W[(size_t)(g*Hd + unit)*Ed + kk + j] : 0.f;
                    tmp[j] = f2bf(v);
                }
            }
            *(bfrag*)(dst + idx) = *(const bfrag*)tmp;
        }
    }
}

// ---------------- GRU v16: 2-column interleave + side-car blocks -------------
// Blocks 0..39: GRU. bid = uc*8 + g8, g8 = side*4+pr -> all 5 uc blocks of a
// group AND both its columns (bg=2pr,2pr+1) share one XCD (bid&7 map, R7).
// Weights depend only on (side,uc,w) -> ONE resident copy serves both columns.
// While column 0's h percolates through L2 (publish->spin->load), the block
// computes column 1's full phase, and vice versa: latency hiding by interleave.
// Per column: R16/R20-proven mechanics verbatim (per-slot dual flags, sc0 h
// path, wave-pair store/drain/publish; waves 0-1 own col0, waves 2-3 own col1;
// spin by wave 2c so the other column's storers never gate it).
// Blocks 40..167: lenva side-car. Blocks 168..215: w1conv side-car.
__global__ __launch_bounds__(256, 1) void k_gru(
        const unsigned short* __restrict__ WF,
        const unsigned short* __restrict__ XF,
        const float* __restrict__ bih_l, const float* __restrict__ bhh_l,
        const float* __restrict__ bih_r, const float* __restrict__ bhh_r,
        const float* __restrict__ wml, const float* __restrict__ wmr,
        unsigned short* __restrict__ HF,
        float* __restrict__ part, int* __restrict__ flags,
        const float* __restrict__ embed, const int* __restrict__ text,
        const int* __restrict__ aspect, const int* __restrict__ xl,
        int* __restrict__ lens, float* __restrict__ va,
        const float* __restrict__ w1, unsigned short* __restrict__ w1b) {
    if (blockIdx.x >= 40) {
        int xb = blockIdx.x - 40;
        int t = threadIdx.x;
        if (xb < 128) {
            // ---- lenva side-car ----
            int b = xb;
            __shared__ int red[3];
            __shared__ int aidx[Ad];
            if (t < 3) red[t] = 0;
            __syncthreads();
            if (t < Sd) {
                if (text[b*Sd + t] != 0) atomicAdd(&red[0], 1);
                if (xl[b*Sd + t]  != 0) atomicAdd(&red[2], 1);
            }
            if (t < Ad) {
                aidx[t] = aspect[b*Ad + t];
                if (aidx[t] != 0) atomicAdd(&red[1], 1);
            }
            __syncthreads();
            if (t < 3) lens[b*4 + t] = red[t];
            float inv = 1.0f / (float)red[1];
            for (int e = t; e < EP; e += 256) {
                float s = 0.f;
                if (e < Ed) {
                    for (int a = 0; a < Ad; ++a) s += embed[(size_t)aidx[a]*Ed + e];
                }
                va[b*EP + e] = s * inv;
            }
        } else {
            // ---- w1conv side-car (48 blocks, grid-stride) ----
            for (int idx = (xb - 128)*256 + t; idx < EP*EP; idx += 48*256) {
                int e = idx / EP, k = idx - e*EP;
                float v = (e < Ed && k < Ed) ? w1[(size_t)e*900 + k] : 0.f;
                w1b[idx] = f2bf(v);
            }
        }
        return;
    }

    int g8 = blockIdx.x & 7;       // XCD group
    int uc = blockIdx.x >> 3;      // 0..4
    int side = g8 >> 2;
    int pr = g8 & 3;
    int bg0 = pr*2, bg1 = pr*2 + 1;
    int tid = threadIdx.x;
    int w = tid >> 6, lane = tid & 63, ul = lane & 15, lq = lane >> 4;
    int utg = uc*4 + w;            // global u-tile 0..19
    int u = utg*16 + ul;           // global unit

    const float* bih = side ? bih_r : bih_l;
    const float* bhh = side ? bhh_r : bhh_l;
    const float* wmv = side ? wmr : wml;

    float bR=0.f, bZ=0.f, bNI=0.f, bNH=0.f, wml_r=0.f;
    if (u < Hd) {
        bR = bih[u] + bhh[u];
        bZ = bih[Hd+u] + bhh[Hd+u];
        bNI = bih[2*Hd+u];
        bNH = bhh[2*Hd+u];
        wml_r = wmv[u];
    }

    // resident weight fragments: 3 gates x 10 kt x 2 matrices (shared by cols)
    bfrag wI[3][10], wH[3][10];
    #pragma unroll
    for (int g = 0; g < 3; ++g) {
        const unsigned short* pI = WF + ((size_t)((side*2+0)*3+g)*20 + utg)*5120 + lane*8;
        const unsigned short* pH = WF + ((size_t)((side*2+1)*3+g)*20 + utg)*5120 + lane*8;
        #pragma unroll
        for (int kt = 0; kt < 10; ++kt) {
            wI[g][kt] = *(const bfrag*)(pI + kt*512);
            wH[g][kt] = *(const bfrag*)(pH + kt*512);
        }
    }

    __shared__ __align__(16) unsigned short hn_s[2][1024];   // per-col [2 kt][64][8]
    int ci0 = side*8 + bg0, ci1 = side*8 + bg1;
    int* flg0L2 = flags + ci0*16;            int* flg0IC = flags + 512 + ci0*16;
    int* flg1L2 = flags + ci1*16;            int* flg1IC = flags + 512 + ci1*16;
    unsigned short* hfb0 = HF + (size_t)(ci0*2)*5120;
    unsigned short* hfb1 = HF + (size_t)(ci1*2)*5120;
    const unsigned short* xb0 = XF + ((size_t)side*Sd*8 + bg0)*5120 + lane*8;
    const unsigned short* xb1 = XF + ((size_t)side*Sd*8 + bg1)*5120 + lane*8;

    // preload x(t=0) for both columns
    bfrag x0[10], x1[10];
    #pragma unroll
    for (int kt = 0; kt < 10; ++kt) {
        x0[kt] = *(const bfrag*)(xb0 + kt*512);
        x1[kt] = *(const bfrag*)(xb1 + kt*512);
    }

    float h0[4] = {0.f,0.f,0.f,0.f}, h1[4] = {0.f,0.f,0.f,0.f};
    const f32x4 zero4 = {0.f,0.f,0.f,0.f};

#define GRU_GI(XC, AR, AZ, ANI) do {                                           \
    _Pragma("unroll")                                                          \
    for (int kt = 0; kt < 10; ++kt) {                                          \
        AR  = __builtin_amdgcn_mfma_f32_16x16x32_bf16(XC[kt], wI[0][kt], AR, 0,0,0); \
        AZ  = __builtin_amdgcn_mfma_f32_16x16x32_bf16(XC[kt], wI[1][kt], AZ, 0,0,0); \
        ANI = __builtin_amdgcn_mfma_f32_16x16x32_bf16(XC[kt], wI[2][kt], ANI, 0,0,0); \
    }                                                                          \
} while (0)

#define GRU_PHASE(T, C, HFB, FLGL2, FLGIC, HREG, AR, AZ, ANI, ANH, CI) do {    \
    if ((T) > 0) {                                                             \
        if (w == 2*(C)) {                                                      \
            int iters = 0;                                                     \
            while (true) {                                                     \
                int v = (T);                                                   \
                if (lane < 2*UC)                                               \
                    v = __hip_atomic_fetch_add((FLGL2) + lane, 0, __ATOMIC_RELAXED, __HIP_MEMORY_SCOPE_WORKGROUP); \
                if (__all(v >= (T))) break;                                    \
                if (((++iters) & 63) == 0) {                                   \
                    int vv = (T);                                              \
                    if (lane < 2*UC)                                           \
                        vv = __hip_atomic_load((FLGIC) + lane, __ATOMIC_RELAXED, __HIP_MEMORY_SCOPE_AGENT); \
                    if (__all(vv >= (T))) break;                               \
                }                                                              \
            }                                                                  \
        }                                                                      \
        __syncthreads();                                                       \
    }                                                                          \
    asm volatile("" ::: "memory");                                             \
    {                                                                          \
        const unsigned short* hg = (HFB) + (size_t)((T) & 1)*5120 + lane*8;    \
        bfrag hf[10];                                                          \
        _Pragma("unroll")                                                      \
        for (int kt = 0; kt < 10; ++kt)                                        \
            hf[kt] = l2_load16b(hg + kt*512);                                  \
        asm volatile("s_waitcnt vmcnt(0)" ::: "memory");                       \
        __builtin_amdgcn_sched_barrier(0);                                     \
        _Pragma("unroll")                                                      \
        for (int kt = 0; kt < 10; ++kt) {                                      \
            AR  = __builtin_amdgcn_mfma_f32_16x16x32_bf16(hf[kt], wH[0][kt], AR, 0,0,0); \
            AZ  = __builtin_amdgcn_mfma_f32_16x16x32_bf16(hf[kt], wH[1][kt], AZ, 0,0,0); \
            ANH = __builtin_amdgcn_mfma_f32_16x16x32_bf16(hf[kt], wH[2][kt], ANH, 0,0,0); \
        }                                                                      \
    }                                                                          \
    {                                                                          \
        int u_local = w*16 + ul;                                               \
        int kt_l = u_local >> 5, ko = u_local & 31;                            \
        _Pragma("unroll")                                                      \
        for (int i = 0; i < 4; ++i) {                                          \
            float rr = sigm(AR[i] + bR);                                       \
            float zz = sigm(AZ[i] + bZ);                                       \
            float nn = fast_tanh(ANI[i] + bNI + rr*(ANH[i] + bNH));            \
            float hv = (1.f - zz)*nn + zz*HREG[i];                             \
            HREG[i] = hv;                                                      \
            int rrow = lq*4 + i;                                               \
            hn_s[C][kt_l*512 + (rrow + ((ko>>3)<<4))*8 + (ko&7)] = f2bf(hv);   \
        }                                                                      \
    }                                                                          \
    __syncthreads();   /* hn_s[C] ready AND all waves' hf loads retired */     \
    if ((w >> 1) == (C)) {                                                     \
        unsigned short* hd = (HFB) + (size_t)(((T)+1) & 1)*5120 + uc*1024;     \
        int sidx = (w & 1)*64 + lane;                                          \
        l2_store16(hd + (size_t)sidx*8, ((const i32x4*)hn_s[C])[sidx]);        \
        asm volatile("s_waitcnt vmcnt(0)" ::: "memory");                       \
        if (lane == 0 && (T) < Sd-1) {                                         \
            __hip_atomic_fetch_add((FLGL2) + uc*2 + (w & 1), 1, __ATOMIC_RELAXED, __HIP_MEMORY_SCOPE_WORKGROUP); \
            __hip_atomic_store((FLGIC) + uc*2 + (w & 1), (T)+1, __ATOMIC_RELAXED, __HIP_MEMORY_SCOPE_AGENT); \
        }                                                                      \
    }                                                                          \
    _Pragma("unroll")                                                          \
    for (int i = 0; i < 4; ++i) {                                              \
        float pv = HREG[i] * wml_r;                                            \
        pv += __shfl_xor(pv, 1, 64);                                           \
        pv += __shfl_xor(pv, 2, 64);                                           \
        pv += __shfl_xor(pv, 4, 64);                                           \
        pv += __shfl_xor(pv, 8, 64);                                           \
        if (ul == 0)                                                           \
            part[((size_t)(((CI)*UC + uc)*4 + w)*16 + lq*4 + i)*Sd + (T)] = pv; \
    }                                                                          \
} while (0)

    #pragma unroll 1
    for (int t = 0; t < Sd; ++t) {
        f32x4 aR0=zero4, aZ0=zero4, aNI0=zero4, aNH0=zero4;
        f32x4 aR1=zero4, aZ1=zero4, aNI1=zero4, aNH1=zero4;
        GRU_GI(x0, aR0, aZ0, aNI0);
        GRU_GI(x1, aR1, aZ1, aNI1);
        GRU_PHASE(t, 0, hfb0, flg0L2, flg0IC, h0, aR0, aZ0, aNI0, aNH0, ci0);
        GRU_PHASE(t, 1, hfb1, flg1L2, flg1IC, h1, aR1, aZ1, aNI1, aNH1, ci1);
        {
            int tn = (t+1 < Sd) ? t+1 : Sd-1;
            const unsigned short* xp0 = xb0 + (size_t)tn*40960;
            const unsigned short* xp1 = xb1 + (size_t)tn*40960;
            #pragma unroll
            for (int kt = 0; kt < 10; ++kt) {
                x0[kt] = *(const bfrag*)(xp0 + kt*512);
                x1[kt] = *(const bfrag*)(xp1 + kt*512);
            }
        }
    }
#undef GRU_GI
#undef GRU_PHASE
}

// ---------------- attn + wmem + u (fused, per-b; attn/vs stay in LDS) --------
__global__ void k_awu(const float* __restrict__ part, const float* __restrict__ bml,
                      const float* __restrict__ bmr, const float* __restrict__ embed,
                      const int* __restrict__ text, const int* __restrict__ lens,
                      const float* __restrict__ w1, const float* __restrict__ b1,
                      const float* __restrict__ va,
                      unsigned short* __restrict__ memw, float* __restrict__ vs,
                      float* __restrict__ u) {
    int b = blockIdx.x;
    int bg = b >> 4, r = b & 15;
    __shared__ float attl_s[Sd], attr_s[Sd];
    __shared__ float w_sh[Sd];
    __shared__ int text_s[Sd];
    __shared__ float va_s[EP], vs_s[EP];
    int t = threadIdx.x;   // blockDim = 320

    // phase 1: attention — both sides for this b, into LDS
    if (t < Sd) {
        float sl = 0.f, sr = 0.f;
        for (int c = 0; c < UC*4; ++c) {
            sl += part[((size_t)(((0*8+bg)*UC*4 + c)*16) + r)*Sd + t];
            sr += part[((size_t)(((1*8+bg)*UC*4 + c)*16) + r)*Sd + t];
        }
        attl_s[t] = sigm(sl + bml[0]) + 0.5f;
        attr_s[t] = sigm(sr + bmr[0]) + 0.5f;
        text_s[t] = text[b*Sd + t];
    }
    va_s[t] = va[b*EP + t];
    __syncthreads();

    // phase 2: position weights
    int memlen = lens[b*4+0], asplen = lens[b*4+1], leftlen = lens[b*4+2];
    int a_start = leftlen - asplen, a_end = leftlen;
    if (t < Sd) {
        int i = t;
        int irr = a_end - 1 - i; irr = irr < 0 ? 0 : (irr > Sd-1 ? Sd-1 : irr);
        int ils = i - a_start;   ils = ils < 0 ? 0 : (ils > Sd-1 ? Sd-1 : ils);
        float arr_ = attr_s[irr], als = attl_s[ils];
        float w = (i < a_start) ? arr_ : ((i < a_end) ? 0.5f*(arr_+als) : als);
        if (i >= memlen) w = 1.0f;
        w_sh[i] = w;
    }
    __syncthreads();

    // phase 3: weighted memory + v_s
    int e = t;
    float acc = 0.f;
    float invm = 1.0f/(float)memlen;
    for (int s = 0; s < Sd; ++s) {
        float v = (e < Ed) ? embed[(size_t)text_s[s]*Ed + e] : 0.f;
        float mw = v * w_sh[s];
        memw[((size_t)b*Sd + s)*EP + e] = f2bf(mw);
        acc += mw;
    }
    float vsv = acc * invm;
    vs[b*EP + e] = vsv;
    vs_s[e] = vsv;
    __syncthreads();

    // phase 4: u = b1 + va@W1a^T + vs@W1s^T
    float accu = 0.f;
    if (e < Ed) {
        accu = b1[e];
        const float* rw = w1 + (size_t)e*900;
        for (int k = 0; k < Ed; ++k) accu += va_s[k]*rw[300+k];
        for (int k = 0; k < Ed; ++k) accu += vs_s[k]*rw[600+k];
    }
    u[b*EP + e] = accu;
}

// ---------------- c[b,s] = w2 . tanh(memw@W1m^T + u)  (MFMA) ----------------
__global__ __launch_bounds__(256) void k_c(const unsigned short* __restrict__ memw,
                   const unsigned short* __restrict__ w1b,
                   const float* __restrict__ u, const float* __restrict__ w2,
                   float* __restrict__ cout) {
    int b = blockIdx.x >> 2;
    int s0 = (blockIdx.x & 3) * 64;
    __shared__ __align__(16) unsigned short A_s[64*328];
    __shared__ __align__(16) unsigned short Bp_s[EP*32];
    __shared__ float u_s[EP], w2_s[EP];
    for (int i = threadIdx.x; i < EP; i += 256) {
        u_s[i] = u[b*EP + i];
        w2_s[i] = (i < Ed) ? w2[i] : 0.f;
    }
    const unsigned short* Ag = memw + ((size_t)b*Sd + s0)*EP;
    for (int c8 = threadIdx.x; c8 < 64*40; c8 += 256) {
        int r = c8 / 40, kk = (c8 - r*40)*8;
        *(bfrag*)(A_s + r*328 + kk) = *(const bfrag*)(Ag + (size_t)r*EP + kk);
    }

    int wave = threadIdx.x >> 6, lane = threadIdx.x & 63;
    int ul = lane & 15, lq = lane >> 4;
    const f32x4 zero4 = {0.f,0.f,0.f,0.f};
    f32x4 acc[20];
    #pragma unroll
    for (int n = 0; n < 20; ++n) acc[n] = zero4;

    for (int kp = 0; kp < 10; ++kp) {
        __syncthreads();
        for (int c8 = threadIdx.x; c8 < EP*4; c8 += 256) {
            int e = c8 >> 2, kk = (c8 & 3)*8;
            *(bfrag*)(Bp_s + e*32 + kk) = *(const bfrag*)(w1b + (size_t)e*EP + kp*32 + kk);
        }
        __syncthreads();
        bfrag a = *(const bfrag*)(A_s + (wave*16 + ul)*328 + kp*32 + lq*8);
        #pragma unroll
        for (int n = 0; n < 20; ++n) {
            bfrag bb = *(const bfrag*)(Bp_s + (n*16 + ul)*32 + lq*8);
            acc[n] = __builtin_amdgcn_mfma_f32_16x16x32_bf16(a, bb, acc[n], 0, 0, 0);
        }
    }
    float cs[4] = {0.f,0.f,0.f,0.f};
    #pragma unroll
    for (int n = 0; n < 20; ++n) {
        int e = n*16 + ul;
        #pragma unroll
        for (int i = 0; i < 4; ++i)
            cs[i] += w2_s[e] * fast_tanh(acc[n][i] + u_s[e]);
    }
    #pragma unroll
    for (int i = 0; i < 4; ++i) {
        float v = cs[i];
        v += __shfl_xor(v, 1, 64); v += __shfl_xor(v, 2, 64);
        v += __shfl_xor(v, 4, 64); v += __shfl_xor(v, 8, 64);
        if (ul == 0) cout[(size_t)b*Sd + s0 + wave*16 + lq*4 + i] = v;
    }
}

// ---------------- softmax + final head (fused, per-b; alpha stays in LDS) ----
__global__ void k_af(const float* __restrict__ cin, const unsigned short* __restrict__ memw,
                     const float* __restrict__ vs, const float* __restrict__ wm,
                     const float* __restrict__ bm, const float* __restrict__ wd,
                     const float* __restrict__ bd, float* __restrict__ out) {
    int b = blockIdx.x;
    int t = threadIdx.x;   // blockDim = 320
    __shared__ float buf[Sd];
    __shared__ float al_s[Sd];
    __shared__ float vns_s[Ed];
    __shared__ float vms_s[Ed];
    __shared__ float lg_s[Pd];

    // phase 1: softmax over c[b,:]
    float v = 0.f;
    if (t < Sd) { v = cin[(size_t)b*Sd + t]; buf[t] = v; }
    __syncthreads();
    for (int s2 = 128; s2 > 0; s2 >>= 1) {
        if (t < s2) buf[t] = fmaxf(buf[t], buf[t+s2]);
        __syncthreads();
    }
    float mx = buf[0];
    __syncthreads();
    float ex = 0.f;
    if (t < Sd) { ex = __expf(v - mx); buf[t] = ex; }
    __syncthreads();
    for (int s2 = 128; s2 > 0; s2 >>= 1) {
        if (t < s2) buf[t] += buf[t+s2];
        __syncthreads();
    }
    if (t < Sd) al_s[t] = ex / buf[0];
    __syncthreads();

    // phase 2: v_ts + v_ns + v_ms + logits + softmax
    int e = t;
    if (e < Ed) {
        float acc = 0.f;
        const unsigned short* mp = memw + (size_t)b*Sd*EP + e;
        for (int s = 0; s < Sd; ++s) acc += bf2f(mp[(size_t)s*EP]) * al_s[s];
        vns_s[e] = acc + vs[b*EP + e];
    }
    __syncthreads();
    if (e < Ed) {
        float acc = bm[e];
        const float* r = wm + (size_t)e*Ed;
        for (int k = 0; k < Ed; ++k) acc += vns_s[k]*r[k];
        vms_s[e] = fast_tanh(acc);
    }
    __syncthreads();
    if (e < Pd) {
        float acc = bd[e];
        const float* r = wd + (size_t)e*Ed;
        for (int k = 0; k < Ed; ++k) acc += vms_s[k]*r[k];
        lg_s[e] = acc;
    }
    __syncthreads();
    if (e < Pd) {
        float m = fmaxf(lg_s[0], fmaxf(lg_s[1], lg_s[2]));
        float den = __expf(lg_s[0]-m)+__expf(lg_s[1]-m)+__expf(lg_s[2]-m);
        out[b*Pd + e] = __expf(lg_s[e]-m)/den;
    }
}

extern "C" void kernel_launch(void* const* d_in, const int* in_sizes, int n_in,
                              void* d_out, int out_size, void* d_ws, size_t ws_size,
                              hipStream_t stream) {
    const float* embed = (const float*)d_in[0];
    const float* w1    = (const float*)d_in[1];
    const float* b1    = (const float*)d_in[2];
    const float* w2    = (const float*)d_in[3];
    const float* wm    = (const float*)d_in[4];
    const float* bm    = (const float*)d_in[5];
    const float* wd    = (const float*)d_in[6];
    const float* bd    = (const float*)d_in[7];
    const float* wih_l = (const float*)d_in[8];
    const float* whh_l = (const float*)d_in[9];
    const float* bih_l = (const float*)d_in[10];
    const float* bhh_l = (const float*)d_in[11];
    const float* wih_r = (const float*)d_in[12];
    const float* whh_r = (const float*)d_in[13];
    const float* bih_r = (const float*)d_in[14];
    const float* bhh_r = (const float*)d_in[15];
    const float* wml   = (const float*)d_in[16];
    const float* bml   = (const float*)d_in[17];
    const float* wmr   = (const float*)d_in[18];
    const float* bmr   = (const float*)d_in[19];
    const int* text    = (const int*)d_in[20];
    const int* aspect  = (const int*)d_in[21];
    const int* xl      = (const int*)d_in[22];
    const int* xr      = (const int*)d_in[23];

    if (ws_size < (size_t)WS_NEEDED) return;
    char* ws = (char*)d_ws;
    int* lens            = (int*)(ws + OFF_LENS);
    int* flags           = (int*)(ws + OFF_FLAGS);
    float* va            = (float*)(ws + OFF_VA);
    float* vs            = (float*)(ws + OFF_VS);
    float* u             = (float*)(ws + OFF_U);
    float* c             = (float*)(ws + OFF_C);
    unsigned short* HF   = (unsigned short*)(ws + OFF_HF);
    float* part          = (float*)(ws + OFF_PART);
    unsigned short* WF   = (unsigned short*)(ws + OFF_WF);
    unsigned short* w1b  = (unsigned short*)(ws + OFF_W1B);
    unsigned short* XF   = (unsigned short*)(ws + OFF_XF);
    unsigned short* memw = (unsigned short*)(ws + OFF_MEMW);

    hipMemsetAsync(ws + OFF_FLAGS, 0, 4096, stream);
    hipMemsetAsync(ws + OFF_HF, 0, 327680, stream);

    k_prep <<<752, 256, 0, stream>>>(embed, xl, xr, XF,
                                     wih_l, whh_l, wih_r, whh_r, WF);
    k_gru  <<<216, 256, 0, stream>>>(WF, XF, bih_l, bhh_l, bih_r, bhh_r,
                                     wml, wmr, HF, part, flags,
                                     embed, text, aspect, xl, lens, va, w1, w1b);
    k_awu  <<<128, 320, 0, stream>>>(part, bml, bmr, embed, text, lens,
                                     w1, b1, va, memw, vs, u);
    k_c    <<<512, 256, 0, stream>>>(memw, w1b, u, w2, c);
    k_af   <<<128, 320, 0, stream>>>(c, memw, vs, wm, bm, wd, bd, (float*)d_out);
}

// Round 22
// 781.137 us; speedup vs baseline: 2.8259x; 2.8259x over previous
//
#include <hip/hip_runtime.h>
#include <hip/hip_bf16.h>
#include <math.h>

#define Bd 128
#define Sd 256
#define Ad 8
#define Ed 300
#define Hd 300
#define EP 320
#define Pd 3
#define UC 5      // unit chunks (64 units each)
#define BG 8      // batch groups (16 rows each)

typedef __attribute__((ext_vector_type(8))) short bfrag;   // 8 bf16 (4 VGPRs)
typedef __attribute__((ext_vector_type(4))) float f32x4;   // MFMA acc / 16B float chunk
typedef __attribute__((ext_vector_type(4))) int i32x4;     // 16B chunk

// ---- workspace layout (bytes) ----
#define OFF_LENS   0u           // int[128*4]
#define OFF_FLAGS  4096u        // int[1024]: L2 flags [(side*8+bg)*16 + uc*2+w]; IC at +512 ints
#define OFF_VA     8192u        // float[128*320]
#define OFF_VS     172032u      // float[128*320]
#define OFF_U      335872u      // float[128*320]
#define OFF_C      892928u      // float[128*256]
#define OFF_HF     1024000u     // ushort[2 side][8 bg][2 parity][10 kt][64 lane][8]
#define OFF_PART   1351680u     // float[2*8*5*4][16][256] = 10.49MB
#define OFF_WF     11837440u    // ushort[2 side][2 mat][3 g][20 ut][10 kt][64][8]
#define OFF_W1B    14295040u    // ushort[320*320]
#define OFF_XF     14499840u    // ushort[2 side][256 t][8 bg][10 kt][64][8] = 41.94MB
#define OFF_MEMW   14499840u    // overlays XF (XF dead after k_gru)
#define WS_NEEDED  56442880u

__device__ __forceinline__ unsigned short f2bf(float f) {
    __hip_bfloat16 h = __float2bfloat16(f);
    return *reinterpret_cast<unsigned short*>(&h);
}
__device__ __forceinline__ float bf2f(unsigned short u) {
    __hip_bfloat16 h = *reinterpret_cast<__hip_bfloat16*>(&u);
    return __bfloat162float(h);
}
__device__ __forceinline__ float sigm(float x) {
    return __builtin_amdgcn_rcpf(1.f + __expf(-x));
}
__device__ __forceinline__ float fast_tanh(float x) {
    x = fminf(fmaxf(x, -15.f), 15.f);
    float e = __expf(2.f * x);
    return (e - 1.f) * __builtin_amdgcn_rcpf(e + 1.f);
}

// XCD-L2-coherent DATA ops (sc0 store->shared-L2, proven R9/R13).
// R11 lesson: flags must NEVER be polled with plain loads -> atomic RMW only
// (atomics execute at the L2 coherence point, L1 cannot serve them).
__device__ __forceinline__ bfrag l2_load16b(const void* p) {
    bfrag v;
    asm volatile("global_load_dwordx4 %0, %1, off sc0"
                 : "=v"(v) : "v"(p) : "memory");
    return v;  // NOT ready until s_waitcnt vmcnt
}
__device__ __forceinline__ void l2_store16(void* p, i32x4 v) {
    asm volatile("global_store_dwordx4 %0, %1, off sc0"
                 :: "v"(p), "v"(v) : "memory");
}

// ---------------- prep: x embeddings + GRU weights (fused producers) --------
__global__ void k_prep(const float* __restrict__ embed, const int* __restrict__ xl,
                       const int* __restrict__ xr, unsigned short* __restrict__ XF,
                       const float* __restrict__ wih_l, const float* __restrict__ whh_l,
                       const float* __restrict__ wih_r, const float* __restrict__ whh_r,
                       unsigned short* __restrict__ WF) {
    if (blockIdx.x < 512) {
        // ---- x embeddings, fragment-major (vectorized stores) ----
        int side = blockIdx.x >> 8;
        int t = blockIdx.x & 255;
        const int* xs = side ? xr : xl;
        __shared__ int rows_s[Bd];
        if (threadIdx.x < Bd) rows_s[threadIdx.x] = xs[threadIdx.x*Sd + t];
        __syncthreads();
        unsigned short* dst = XF + ((size_t)(side*Sd + t))*40960;
        for (int v8 = threadIdx.x; v8 < 5120; v8 += 256) {
            int idx = v8 << 3;
            int bt = idx / 5120;
            int r1 = idx - bt*5120;
            int kt = r1 >> 9;
            int r2 = r1 & 511;
            int lane = r2 >> 3;
            int b = bt*16 + (lane & 15);
            int kk = kt*32 + (lane >> 4)*8;
            const float* src = embed + (size_t)rows_s[b]*Ed + kk;
            unsigned short tmp[8];
            if (kk + 8 <= Ed) {
                f32x4 f0 = *(const f32x4*)(src);
                f32x4 f1 = *(const f32x4*)(src + 4);
                #pragma unroll
                for (int j = 0; j < 4; ++j) { tmp[j] = f2bf(f0[j]); tmp[4+j] = f2bf(f1[j]); }
            } else {
                #pragma unroll
                for (int j = 0; j < 8; ++j)
                    tmp[j] = (kk + j < Ed) ? f2bf(src[j]) : (unsigned short)0;
            }
            *(bfrag*)(dst + idx) = *(const bfrag*)tmp;
        }
    } else {
        // ---- GRU weights, fragment-major (vectorized stores) ----
        int bid = blockIdx.x - 512;        // ((side*2+mat)*3+g)*20+ut
        int side = bid / 120;
        int r = bid - side*120;
        int mat = r / 60; r -= mat*60;
        int g = r / 20;
        int ut = r - g*20;
        const float* W = mat ? (side ? whh_r : whh_l) : (side ? wih_r : wih_l);
        unsigned short* dst = WF + (size_t)bid*5120;
        for (int v8 = threadIdx.x; v8 < 640; v8 += 256) {
            int idx = v8 << 3;
            int kt = idx >> 9;
            int r2 = idx & 511;
            int lane = r2 >> 3;
            int unit = ut*16 + (lane & 15);
            int kk = kt*32 + (lane >> 4)*8;
            unsigned short tmp[8];
            if (unit < Hd && kk + 8 <= Ed) {
                const float* src = W + (size_t)(g*Hd + unit)*Ed + kk;
                f32x4 f0 = *(const f32x4*)(src);
                f32x4 f1 = *(const f32x4*)(src + 4);
                #pragma unroll
                for (int j = 0; j < 4; ++j) { tmp[j] = f2bf(f0[j]); tmp[4+j] = f2bf(f1[j]); }
            } else {
                #pragma unroll
                for (int j = 0; j < 8; ++j) {
                    float v = (unit < Hd && kk + j < Ed) ? W[(size_t)(g*Hd + unit)*Ed + kk + j] : 0.f;
                    tmp[j] = f2bf(v);
                }
            }
            *(bfrag*)(dst + idx) = *(const bfrag*)tmp;
        }
    }
}

// ---------------- GRU v15 (BEST chain, R16/R18/R20) + side-car blocks --------
// Blocks 0..79: GRU (dispatch order preserved -> bid&7 XCD map unchanged).
// Blocks 80..207: lenva side-car (consumed by k_awu, after this kernel).
// Blocks 208..255: w1conv side-car (consumed by k_c, after this kernel).
// Side-cars run on otherwise-idle CUs concurrent with the GRU chain.
__global__ __launch_bounds__(256, 1) void k_gru(
        const unsigned short* __restrict__ WF,
        const unsigned short* __restrict__ XF,
        const float* __restrict__ bih_l, const float* __restrict__ bhh_l,
        const float* __restrict__ bih_r, const float* __restrict__ bhh_r,
        const float* __restrict__ wml, const float* __restrict__ wmr,
        unsigned short* __restrict__ HF,
        float* __restrict__ part, int* __restrict__ flags,
        const float* __restrict__ embed, const int* __restrict__ text,
        const int* __restrict__ aspect, const int* __restrict__ xl,
        int* __restrict__ lens, float* __restrict__ va,
        const float* __restrict__ w1, unsigned short* __restrict__ w1b) {
    if (blockIdx.x >= 80) {
        int xb = blockIdx.x - 80;
        int t = threadIdx.x;
        if (xb < 128) {
            // ---- lenva side-car ----
            int b = xb;
            __shared__ int red[3];
            __shared__ int aidx[Ad];
            if (t < 3) red[t] = 0;
            __syncthreads();
            if (t < Sd) {
                if (text[b*Sd + t] != 0) atomicAdd(&red[0], 1);
                if (xl[b*Sd + t]  != 0) atomicAdd(&red[2], 1);
            }
            if (t < Ad) {
                aidx[t] = aspect[b*Ad + t];
                if (aidx[t] != 0) atomicAdd(&red[1], 1);
            }
            __syncthreads();
            if (t < 3) lens[b*4 + t] = red[t];
            float inv = 1.0f / (float)red[1];
            for (int e = t; e < EP; e += 256) {
                float s = 0.f;
                if (e < Ed) {
                    for (int a = 0; a < Ad; ++a) s += embed[(size_t)aidx[a]*Ed + e];
                }
                va[b*EP + e] = s * inv;
            }
        } else {
            // ---- w1conv side-car (48 blocks, grid-stride) ----
            for (int idx = (xb - 128)*256 + t; idx < EP*EP; idx += 48*256) {
                int e = idx / EP, k = idx - e*EP;
                float v = (e < Ed && k < Ed) ? w1[(size_t)e*900 + k] : 0.f;
                w1b[idx] = f2bf(v);
            }
        }
        return;
    }

    int bg = blockIdx.x & 7;
    int r8 = blockIdx.x >> 3;      // 0..9
    int side = r8 & 1;
    int uc = r8 >> 1;              // 0..4
    int tid = threadIdx.x;
    int w = tid >> 6, lane = tid & 63, ul = lane & 15, lq = lane >> 4;
    int utg = uc*4 + w;            // global u-tile 0..19
    int u = utg*16 + ul;           // global unit

    const float* bih = side ? bih_r : bih_l;
    const float* bhh = side ? bhh_r : bhh_l;
    const float* wmv = side ? wmr : wml;

    float bR=0.f, bZ=0.f, bNI=0.f, bNH=0.f, wml_r=0.f;
    if (u < Hd) {
        bR = bih[u] + bhh[u];
        bZ = bih[Hd+u] + bhh[Hd+u];
        bNI = bih[2*Hd+u];
        bNH = bhh[2*Hd+u];
        wml_r = wmv[u];
    }

    // resident weight fragments: 3 gates x 10 kt x 2 matrices
    bfrag wI[3][10], wH[3][10];
    #pragma unroll
    for (int g = 0; g < 3; ++g) {
        const unsigned short* pI = WF + ((size_t)((side*2+0)*3+g)*20 + utg)*5120 + lane*8;
        const unsigned short* pH = WF + ((size_t)((side*2+1)*3+g)*20 + utg)*5120 + lane*8;
        #pragma unroll
        for (int kt = 0; kt < 10; ++kt) {
            wI[g][kt] = *(const bfrag*)(pI + kt*512);
            wH[g][kt] = *(const bfrag*)(pH + kt*512);
        }
    }

    __shared__ __align__(16) unsigned short hn_s[1024];   // [2 kt][64][8]
    int* flgL2 = flags + (side*8 + bg)*16;                // L2 flags, slots 0..9
    int* flgIC = flags + 512 + (side*8 + bg)*16;          // IC backup flags
    unsigned short* hfb = HF + (size_t)((side*8 + bg)*2)*5120;  // [parity][5120]
    const unsigned short* xbase = XF + ((size_t)side*Sd*8 + bg)*5120 + lane*8;

    // preload x(t=0) into xA
    bfrag xA[10], xB[10];
    #pragma unroll
    for (int kt = 0; kt < 10; ++kt)
        xA[kt] = *(const bfrag*)(xbase + 0 + kt*512);

    float hreg[4] = {0.f,0.f,0.f,0.f};
    const f32x4 zero4 = {0.f,0.f,0.f,0.f};

#define GRU_STEP(T, XIN, XOUT) do {                                            \
    f32x4 aR = zero4, aZ = zero4, aNI = zero4, aNH = zero4;                    \
    _Pragma("unroll")                                                          \
    for (int kt = 0; kt < 10; ++kt) {                                          \
        aR  = __builtin_amdgcn_mfma_f32_16x16x32_bf16(XIN[kt], wI[0][kt], aR, 0,0,0); \
        aZ  = __builtin_amdgcn_mfma_f32_16x16x32_bf16(XIN[kt], wI[1][kt], aZ, 0,0,0); \
        aNI = __builtin_amdgcn_mfma_f32_16x16x32_bf16(XIN[kt], wI[2][kt], aNI, 0,0,0); \
    }                                                                          \
    if ((T) > 0) {                                                             \
        if (w == 0) {                                                          \
            int iters = 0;                                                     \
            while (true) {                                                     \
                int v = (T);                                                   \
                if (lane < 2*UC)                                               \
                    v = __hip_atomic_fetch_add(flgL2 + lane, 0, __ATOMIC_RELAXED, __HIP_MEMORY_SCOPE_WORKGROUP); \
                if (__all(v >= (T))) break;                                    \
                if (((++iters) & 63) == 0) {                                   \
                    int vv = (T);                                              \
                    if (lane < 2*UC)                                           \
                        vv = __hip_atomic_load(flgIC + lane, __ATOMIC_RELAXED, __HIP_MEMORY_SCOPE_AGENT); \
                    if (__all(vv >= (T))) break;                               \
                }                                                              \
            }                                                                  \
        }                                                                      \
        __syncthreads();                                                       \
    }                                                                          \
    asm volatile("" ::: "memory");                                             \
    const unsigned short* hg = hfb + (size_t)((T) & 1)*5120 + lane*8;          \
    bfrag hf[10];                                                              \
    _Pragma("unroll")                                                          \
    for (int kt = 0; kt < 10; ++kt)                                            \
        hf[kt] = l2_load16b(hg + kt*512);                                      \
    asm volatile("s_waitcnt vmcnt(0)" ::: "memory");                           \
    __builtin_amdgcn_sched_barrier(0);                                         \
    _Pragma("unroll")                                                          \
    for (int kt = 0; kt < 10; ++kt) {                                          \
        aR  = __builtin_amdgcn_mfma_f32_16x16x32_bf16(hf[kt], wH[0][kt], aR, 0,0,0); \
        aZ  = __builtin_amdgcn_mfma_f32_16x16x32_bf16(hf[kt], wH[1][kt], aZ, 0,0,0); \
        aNH = __builtin_amdgcn_mfma_f32_16x16x32_bf16(hf[kt], wH[2][kt], aNH, 0,0,0); \
    }                                                                          \
    {                                                                          \
        int u_local = w*16 + ul;                                               \
        int kt_l = u_local >> 5, ko = u_local & 31;                            \
        _Pragma("unroll")                                                      \
        for (int i = 0; i < 4; ++i) {                                          \
            float rr = sigm(aR[i] + bR);                                       \
            float zz = sigm(aZ[i] + bZ);                                       \
            float nn = fast_tanh(aNI[i] + bNI + rr*(aNH[i] + bNH));            \
            float hv = (1.f - zz)*nn + zz*hreg[i];                             \
            hreg[i] = hv;                                                      \
            int rrow = lq*4 + i;                                               \
            hn_s[kt_l*512 + (rrow + ((ko>>3)<<4))*8 + (ko&7)] = f2bf(hv);      \
        }                                                                      \
    }                                                                          \
    __syncthreads();      /* hn_s ready AND all waves' hf loads retired */     \
    if (w < 2) {                                                               \
        unsigned short* hd = hfb + (size_t)(((T)+1) & 1)*5120 + uc*1024;       \
        l2_store16(hd + (size_t)tid*8, ((const i32x4*)hn_s)[tid]);             \
        asm volatile("s_waitcnt vmcnt(0)" ::: "memory");                       \
        if (lane == 0 && (T) < Sd-1) {                                         \
            __hip_atomic_fetch_add(flgL2 + uc*2 + w, 1, __ATOMIC_RELAXED, __HIP_MEMORY_SCOPE_WORKGROUP); \
            __hip_atomic_store(flgIC + uc*2 + w, (T)+1, __ATOMIC_RELAXED, __HIP_MEMORY_SCOPE_AGENT); \
        }                                                                      \
    }                                                                          \
    {                                                                          \
        int tn = ((T)+1 < Sd) ? (T)+1 : Sd-1;                                  \
        const unsigned short* xp = xbase + (size_t)tn*40960;                   \
        _Pragma("unroll")                                                      \
        for (int kt = 0; kt < 10; ++kt)                                        \
            XOUT[kt] = *(const bfrag*)(xp + kt*512);                           \
    }                                                                          \
    _Pragma("unroll")                                                          \
    for (int i = 0; i < 4; ++i) {                                              \
        float pv = hreg[i] * wml_r;                                            \
        pv += __shfl_xor(pv, 1, 64);                                           \
        pv += __shfl_xor(pv, 2, 64);                                           \
        pv += __shfl_xor(pv, 4, 64);                                           \
        pv += __shfl_xor(pv, 8, 64);                                           \
        if (ul == 0)                                                           \
            part[((size_t)((((side*8+bg)*UC + uc)*4 + w)*16) + lq*4 + i)*Sd + (T)] = pv; \
    }                                                                          \
} while (0)

    #pragma unroll 1
    for (int tt = 0; tt < Sd; tt += 2) {
        GRU_STEP(tt,   xA, xB);
        GRU_STEP(tt+1, xB, xA);
    }
#undef GRU_STEP
}

// ---------------- attn + wmem + u (fused, per-b; attn/vs stay in LDS) --------
__global__ void k_awu(const float* __restrict__ part, const float* __restrict__ bml,
                      const float* __restrict__ bmr, const float* __restrict__ embed,
                      const int* __restrict__ text, const int* __restrict__ lens,
                      const float* __restrict__ w1, const float* __restrict__ b1,
                      const float* __restrict__ va,
                      unsigned short* __restrict__ memw, float* __restrict__ vs,
                      float* __restrict__ u) {
    int b = blockIdx.x;
    int bg = b >> 4, r = b & 15;
    __shared__ float attl_s[Sd], attr_s[Sd];
    __shared__ float w_sh[Sd];
    __shared__ int text_s[Sd];
    __shared__ float va_s[EP], vs_s[EP];
    int t = threadIdx.x;   // blockDim = 320

    // phase 1: attention — both sides for this b, into LDS
    if (t < Sd) {
        float sl = 0.f, sr = 0.f;
        for (int c = 0; c < UC*4; ++c) {
            sl += part[((size_t)(((0*8+bg)*UC*4 + c)*16) + r)*Sd + t];
            sr += part[((size_t)(((1*8+bg)*UC*4 + c)*16) + r)*Sd + t];
        }
        attl_s[t] = sigm(sl + bml[0]) + 0.5f;
        attr_s[t] = sigm(sr + bmr[0]) + 0.5f;
        text_s[t] = text[b*Sd + t];
    }
    va_s[t] = va[b*EP + t];
    __syncthreads();

    // phase 2: position weights
    int memlen = lens[b*4+0], asplen = lens[b*4+1], leftlen = lens[b*4+2];
    int a_start = leftlen - asplen, a_end = leftlen;
    if (t < Sd) {
        int i = t;
        int irr = a_end - 1 - i; irr = irr < 0 ? 0 : (irr > Sd-1 ? Sd-1 : irr);
        int ils = i - a_start;   ils = ils < 0 ? 0 : (ils > Sd-1 ? Sd-1 : ils);
        float arr_ = attr_s[irr], als = attl_s[ils];
        float w = (i < a_start) ? arr_ : ((i < a_end) ? 0.5f*(arr_+als) : als);
        if (i >= memlen) w = 1.0f;
        w_sh[i] = w;
    }
    __syncthreads();

    // phase 3: weighted memory + v_s
    int e = t;
    float acc = 0.f;
    float invm = 1.0f/(float)memlen;
    for (int s = 0; s < Sd; ++s) {
        float v = (e < Ed) ? embed[(size_t)text_s[s]*Ed + e] : 0.f;
        float mw = v * w_sh[s];
        memw[((size_t)b*Sd + s)*EP + e] = f2bf(mw);
        acc += mw;
    }
    float vsv = acc * invm;
    vs[b*EP + e] = vsv;
    vs_s[e] = vsv;
    __syncthreads();

    // phase 4: u = b1 + va@W1a^T + vs@W1s^T
    float accu = 0.f;
    if (e < Ed) {
        accu = b1[e];
        const float* rw = w1 + (size_t)e*900;
        for (int k = 0; k < Ed; ++k) accu += va_s[k]*rw[300+k];
        for (int k = 0; k < Ed; ++k) accu += vs_s[k]*rw[600+k];
    }
    u[b*EP + e] = accu;
}

// ---------------- c[b,s] = w2 . tanh(memw@W1m^T + u)  (MFMA) ----------------
__global__ __launch_bounds__(256) void k_c(const unsigned short* __restrict__ memw,
                   const unsigned short* __restrict__ w1b,
                   const float* __restrict__ u, const float* __restrict__ w2,
                   float* __restrict__ cout) {
    int b = blockIdx.x >> 2;
    int s0 = (blockIdx.x & 3) * 64;
    __shared__ __align__(16) unsigned short A_s[64*328];
    __shared__ __align__(16) unsigned short Bp_s[EP*32];
    __shared__ float u_s[EP], w2_s[EP];
    for (int i = threadIdx.x; i < EP; i += 256) {
        u_s[i] = u[b*EP + i];
        w2_s[i] = (i < Ed) ? w2[i] : 0.f;
    }
    const unsigned short* Ag = memw + ((size_t)b*Sd + s0)*EP;
    for (int c8 = threadIdx.x; c8 < 64*40; c8 += 256) {
        int r = c8 / 40, kk = (c8 - r*40)*8;
        *(bfrag*)(A_s + r*328 + kk) = *(const bfrag*)(Ag + (size_t)r*EP + kk);
    }

    int wave = threadIdx.x >> 6, lane = threadIdx.x & 63;
    int ul = lane & 15, lq = lane >> 4;
    const f32x4 zero4 = {0.f,0.f,0.f,0.f};
    f32x4 acc[20];
    #pragma unroll
    for (int n = 0; n < 20; ++n) acc[n] = zero4;

    for (int kp = 0; kp < 10; ++kp) {
        __syncthreads();
        for (int c8 = threadIdx.x; c8 < EP*4; c8 += 256) {
            int e = c8 >> 2, kk = (c8 & 3)*8;
            *(bfrag*)(Bp_s + e*32 + kk) = *(const bfrag*)(w1b + (size_t)e*EP + kp*32 + kk);
        }
        __syncthreads();
        bfrag a = *(const bfrag*)(A_s + (wave*16 + ul)*328 + kp*32 + lq*8);
        #pragma unroll
        for (int n = 0; n < 20; ++n) {
            bfrag bb = *(const bfrag*)(Bp_s + (n*16 + ul)*32 + lq*8);
            acc[n] = __builtin_amdgcn_mfma_f32_16x16x32_bf16(a, bb, acc[n], 0, 0, 0);
        }
    }
    float cs[4] = {0.f,0.f,0.f,0.f};
    #pragma unroll
    for (int n = 0; n < 20; ++n) {
        int e = n*16 + ul;
        #pragma unroll
        for (int i = 0; i < 4; ++i)
            cs[i] += w2_s[e] * fast_tanh(acc[n][i] + u_s[e]);
    }
    #pragma unroll
    for (int i = 0; i < 4; ++i) {
        float v = cs[i];
        v += __shfl_xor(v, 1, 64); v += __shfl_xor(v, 2, 64);
        v += __shfl_xor(v, 4, 64); v += __shfl_xor(v, 8, 64);
        if (ul == 0) cout[(size_t)b*Sd + s0 + wave*16 + lq*4 + i] = v;
    }
}

// ---------------- softmax + final head (fused, per-b; alpha stays in LDS) ----
__global__ void k_af(const float* __restrict__ cin, const unsigned short* __restrict__ memw,
                     const float* __restrict__ vs, const float* __restrict__ wm,
                     const float* __restrict__ bm, const float* __restrict__ wd,
                     const float* __restrict__ bd, float* __restrict__ out) {
    int b = blockIdx.x;
    int t = threadIdx.x;   // blockDim = 320
    __shared__ float buf[Sd];
    __shared__ float al_s[Sd];
    __shared__ float vns_s[Ed];
    __shared__ float vms_s[Ed];
    __shared__ float lg_s[Pd];

    // phase 1: softmax over c[b,:]
    float v = 0.f;
    if (t < Sd) { v = cin[(size_t)b*Sd + t]; buf[t] = v; }
    __syncthreads();
    for (int s2 = 128; s2 > 0; s2 >>= 1) {
        if (t < s2) buf[t] = fmaxf(buf[t], buf[t+s2]);
        __syncthreads();
    }
    float mx = buf[0];
    __syncthreads();
    float ex = 0.f;
    if (t < Sd) { ex = __expf(v - mx); buf[t] = ex; }
    __syncthreads();
    for (int s2 = 128; s2 > 0; s2 >>= 1) {
        if (t < s2) buf[t] += buf[t+s2];
        __syncthreads();
    }
    if (t < Sd) al_s[t] = ex / buf[0];
    __syncthreads();

    // phase 2: v_ts + v_ns + v_ms + logits + softmax
    int e = t;
    if (e < Ed) {
        float acc = 0.f;
        const unsigned short* mp = memw + (size_t)b*Sd*EP + e;
        for (int s = 0; s < Sd; ++s) acc += bf2f(mp[(size_t)s*EP]) * al_s[s];
        vns_s[e] = acc + vs[b*EP + e];
    }
    __syncthreads();
    if (e < Ed) {
        float acc = bm[e];
        const float* r = wm + (size_t)e*Ed;
        for (int k = 0; k < Ed; ++k) acc += vns_s[k]*r[k];
        vms_s[e] = fast_tanh(acc);
    }
    __syncthreads();
    if (e < Pd) {
        float acc = bd[e];
        const float* r = wd + (size_t)e*Ed;
        for (int k = 0; k < Ed; ++k) acc += vms_s[k]*r[k];
        lg_s[e] = acc;
    }
    __syncthreads();
    if (e < Pd) {
        float m = fmaxf(lg_s[0], fmaxf(lg_s[1], lg_s[2]));
        float den = __expf(lg_s[0]-m)+__expf(lg_s[1]-m)+__expf(lg_s[2]-m);
        out[b*Pd + e] = __expf(lg_s[e]-m)/den;
    }
}

extern "C" void kernel_launch(void* const* d_in, const int* in_sizes, int n_in,
                              void* d_out, int out_size, void* d_ws, size_t ws_size,
                              hipStream_t stream) {
    const float* embed = (const float*)d_in[0];
    const float* w1    = (const float*)d_in[1];
    const float* b1    = (const float*)d_in[2];
    const float* w2    = (const float*)d_in[3];
    const float* wm    = (const float*)d_in[4];
    const float* bm    = (const float*)d_in[5];
    const float* wd    = (const float*)d_in[6];
    const float* bd    = (const float*)d_in[7];
    const float* wih_l = (const float*)d_in[8];
    const float* whh_l = (const float*)d_in[9];
    const float* bih_l = (const float*)d_in[10];
    const float* bhh_l = (const float*)d_in[11];
    const float* wih_r = (const float*)d_in[12];
    const float* whh_r = (const float*)d_in[13];
    const float* bih_r = (const float*)d_in[14];
    const float* bhh_r = (const float*)d_in[15];
    const float* wml   = (const float*)d_in[16];
    const float* bml   = (const float*)d_in[17];
    const float* wmr   = (const float*)d_in[18];
    const float* bmr   = (const float*)d_in[19];
    const int* text    = (const int*)d_in[20];
    const int* aspect  = (const int*)d_in[21];
    const int* xl      = (const int*)d_in[22];
    const int* xr      = (const int*)d_in[23];

    if (ws_size < (size_t)WS_NEEDED) return;
    char* ws = (char*)d_ws;
    int* lens            = (int*)(ws + OFF_LENS);
    int* flags           = (int*)(ws + OFF_FLAGS);
    float* va            = (float*)(ws + OFF_VA);
    float* vs            = (float*)(ws + OFF_VS);
    float* u             = (float*)(ws + OFF_U);
    float* c             = (float*)(ws + OFF_C);
    unsigned short* HF   = (unsigned short*)(ws + OFF_HF);
    float* part          = (float*)(ws + OFF_PART);
    unsigned short* WF   = (unsigned short*)(ws + OFF_WF);
    unsigned short* w1b  = (unsigned short*)(ws + OFF_W1B);
    unsigned short* XF   = (unsigned short*)(ws + OFF_XF);
    unsigned short* memw = (unsigned short*)(ws + OFF_MEMW);

    hipMemsetAsync(ws + OFF_FLAGS, 0, 4096, stream);
    hipMemsetAsync(ws + OFF_HF, 0, 327680, stream);

    k_prep <<<752, 256, 0, stream>>>(embed, xl, xr, XF,
                                     wih_l, whh_l, wih_r, whh_r, WF);
    k_gru  <<<256, 256, 0, stream>>>(WF, XF, bih_l, bhh_l, bih_r, bhh_r,
                                     wml, wmr, HF, part, flags,
                                     embed, text, aspect, xl, lens, va, w1, w1b);
    k_awu  <<<128, 320, 0, stream>>>(part, bml, bmr, embed, text, lens,
                                     w1, b1, va, memw, vs, u);
    k_c    <<<512, 256, 0, stream>>>(memw, w1b, u, w2, c);
    k_af   <<<128, 320, 0, stream>>>(c, memw, vs, wm, bm, wd, bd, (float*)d_out);
}